// Round 4
// baseline (256.448 us; speedup 1.0000x reference)
//
#include <hip/hip_runtime.h>
#include <float.h>
#include <limits.h>

#define NB 64
#define NO 16
#define NP 5460
#define NCLS 81

// ws layout (bytes)
#define WS_ACCUM   0
#define WS_WINNER  256
#define WS_CI      1398272
#define WS_OV      1660672

// ---------------------------------------------------------------------------
// Focal-loss helpers. MUST stay bitwise-identical between the streaming pass
// and the fixup pass so the target-slot correction cancels to ~1 ulp.
// ---------------------------------------------------------------------------
__device__ __forceinline__ float focal_neg(float s) {
    float e = __expf(-fabsf(s));            // exp(-|s|) in (0,1]
    float l1p = __logf(1.f + e);
    float q = __frcp_rn(1.f + e);
    float p = (s >= 0.f) ? q : e * q;       // sigmoid(s)
    return 0.75f * p * p * (fmaxf(s, 0.f) + l1p);
}
__device__ __forceinline__ float focal_pos(float s) {
    float e = __expf(-fabsf(s));
    float l1p = __logf(1.f + e);
    float q = __frcp_rn(1.f + e);
    float omp = (s >= 0.f) ? e * q : q;     // 1 - sigmoid(s)
    return 0.25f * omp * omp * (fmaxf(-s, 0.f) + l1p);
}

// ---------------------------------------------------------------------------
// Kernel A1: exact per-level top-9 via analytic 5x5 grid window (no scans).
// One thread per (bo, level). (Unchanged from R3 — passed absmax 0.0.)
// ---------------------------------------------------------------------------
__global__ __launch_bounds__(256) void topk_kernel(
    const float* __restrict__ boxes,   // [NB*NO, 4] xyxy
    int* __restrict__ ci_buf,          // [1024][64] global prior idx
    float* __restrict__ ov_buf)        // [1024][64] iou with box
{
    const int tid = blockIdx.x * 256 + threadIdx.x;   // 0..6143
    const int l  = tid >> 10;                          // level, uniform per block
    const int bo = tid & 1023;

    const int fms[6]   = {64, 32, 16, 8, 4, 2};
    const int lg2s[6]  = {6, 5, 4, 3, 2, 1};
    const int s0s[6]   = {0, 4096, 5120, 5376, 5440, 5456};
    const int basec[6] = {0, 9, 18, 27, 36, 45};
    const int fm = fms[l];
    const int lg2 = lg2s[l];
    const float fmf = (float)fm;

    const float4 bb = reinterpret_cast<const float4*>(boxes)[bo];
    const float bx0 = bb.x, by0 = bb.y, bx1 = bb.z, by1 = bb.w;
    const float bcx = (bx0 + bx1) * 0.5f;
    const float bcy = (by0 + by1) * 0.5f;
    const float barea = (bx1 - bx0) * (by1 - by0);

    int wx0 = 0, wy0 = 0, wnx = fm, wny = fm;
    if (fm >= 5) {
        int jx = (int)floorf(bcx * fmf);
        int jy = (int)floorf(bcy * fmf);
        jx = jx < 0 ? 0 : (jx > fm - 1 ? fm - 1 : jx);
        jy = jy < 0 ? 0 : (jy > fm - 1 ? fm - 1 : jy);
        wx0 = jx - 2; wx0 = wx0 < 0 ? 0 : (wx0 > fm - 5 ? fm - 5 : wx0);
        wy0 = jy - 2; wy0 = wy0 < 0 ? 0 : (wy0 > fm - 5 ? fm - 5 : wy0);
        wnx = 5; wny = 5;
    }

    float bv[9]; int bix[9];
    #pragma unroll
    for (int j = 0; j < 9; ++j) { bv[j] = FLT_MAX; bix[j] = INT_MAX; }

    for (int yy = 0; yy < wny; ++yy) {
        const int iy = wy0 + yy;
        const float py = ((float)iy + 0.5f) / fmf;
        const float dy = bcy - py;
        const float dy2 = dy * dy;
        for (int xx = 0; xx < wnx; ++xx) {
            const int ix = wx0 + xx;
            const float px = ((float)ix + 0.5f) / fmf;
            const float dx = bcx - px;
            const float d = dx * dx + dy2;
            const int gi = (iy << lg2) + ix;
            #pragma unroll
            for (int j = 8; j >= 0; --j) {
                bool ltp = (j > 0) ? (d < bv[j - 1]) : false;
                bool ltj = (d < bv[j]);
                float sv = ltp ? bv[j - 1] : (ltj ? d : bv[j]);
                int   si = ltp ? bix[j - 1] : (ltj ? gi : bix[j]);
                bv[j] = sv; bix[j] = si;
            }
        }
    }

    const int n = fm * fm;
    const int k = n < 9 ? n : 9;
    const float hw = 0.75f / fmf;
    const int obase = bo * 64 + basec[l];
    const int s0 = s0s[l];

    for (int j = 0; j < k; ++j) {
        const int li = bix[j];
        const int iy = li >> lg2, ix = li & (fm - 1);
        const float pcx = ((float)ix + 0.5f) / fmf;
        const float pcy = ((float)iy + 0.5f) / fmf;
        const float px0 = pcx - hw, py0 = pcy - hw;
        const float px1 = pcx + hw, py1 = pcy + hw;
        const float iw = fmaxf(fminf(bx1, px1) - fmaxf(bx0, px0), 0.f);
        const float ih = fmaxf(fminf(by1, py1) - fmaxf(by0, py0), 0.f);
        const float inter = iw * ih;
        const float parea = (px1 - px0) * (py1 - py0);
        const float ovv = inter / (barea + parea - inter + 1e-10f);
        ci_buf[obase + j] = s0 + li;
        ov_buf[obase + j] = ovv;
    }
}

// ---------------------------------------------------------------------------
// Kernel A2: threshold + positives + DIoU. One wave per (b,o); 4 waves/block.
// (Unchanged from R3 — passed absmax 0.0.)
// ---------------------------------------------------------------------------
__global__ __launch_bounds__(256) void assign2_kernel(
    const float* __restrict__ locs,    // [NB, NP, 4]
    const float* __restrict__ boxes,   // [NB*NO, 4]
    const float* __restrict__ priors,  // [NP, 4]
    const int* __restrict__ ci_buf,
    const float* __restrict__ ov_buf,
    int* __restrict__ winner,          // [NB, NP], init -1
    double* __restrict__ accum)        // [0]=conf [1]=loc [2]=cnt
{
    const int w = threadIdx.x >> 6, lane = threadIdx.x & 63;
    const int bo = blockIdx.x * 4 + w;
    const int b = bo >> 4, o = bo & 15;

    const float4 bb = reinterpret_cast<const float4*>(boxes)[bo];
    const float bx0 = bb.x, by0 = bb.y, bx1 = bb.z, by1 = bb.w;
    const float bcx = (bx0 + bx1) * 0.5f, bcy = (by0 + by1) * 0.5f;
    const float barea = (bx1 - bx0) * (by1 - by0);

    int my_ci = 0; float ov = 0.f;
    if (lane < 49) {
        my_ci = ci_buf[bo * 64 + lane];
        ov    = ov_buf[bo * 64 + lane];
    }

    float sum = 0.f;
    for (int i = 0; i < 49; ++i) sum += __shfl(ov, i);
    const float mean = sum / 49.f;
    float ss = 0.f;
    for (int i = 0; i < 49; ++i) { float dd = __shfl(ov, i) - mean; ss += dd * dd; }
    const float thr = mean + sqrtf(ss / 48.f);

    float lloc = 0.f; int lcnt = 0;
    if (lane < 49) {
        const float4 pp = reinterpret_cast<const float4*>(priors)[my_ci];
        const bool inside = (bx0 <= pp.x) && (pp.x <= bx1) &&
                            (by0 <= pp.y) && (pp.y <= by1);
        if (inside && ov > thr) {
            atomicMax(&winner[b * NP + my_ci], o);
            const float4 g = reinterpret_cast<const float4*>(locs)[b * NP + my_ci];
            const float cx = g.x * pp.z * 0.1f + pp.x;
            const float cy = g.y * pp.w * 0.1f + pp.y;
            const float ww = __expf(g.z * 0.2f) * pp.z;
            const float hh = __expf(g.w * 0.2f) * pp.w;
            const float p0 = cx - ww * 0.5f, p1 = cy - hh * 0.5f;
            const float p2 = cx + ww * 0.5f, p3 = cy + hh * 0.5f;
            const float iw = fmaxf(fminf(p2, bx1) - fmaxf(p0, bx0), 0.f);
            const float ih = fmaxf(fminf(p3, by1) - fmaxf(p1, by0), 0.f);
            const float inter = iw * ih;
            const float ap = fmaxf(p2 - p0, 0.f) * fmaxf(p3 - p1, 0.f);
            const float iou = inter / (ap + barea - inter + 1e-7f);
            const float cpx = (p0 + p2) * 0.5f, cpy = (p1 + p3) * 0.5f;
            const float d2 = (cpx - bcx) * (cpx - bcx) + (cpy - bcy) * (cpy - bcy);
            const float ex0 = fminf(p0, bx0), ey0 = fminf(p1, by0);
            const float ex1 = fmaxf(p2, bx1), ey1 = fmaxf(p3, by1);
            const float dg = (ex1 - ex0) * (ex1 - ex0) + (ey1 - ey0) * (ey1 - ey0) + 1e-7f;
            lloc = 1.f - iou + d2 / dg;
            lcnt = 1;
        }
    }
    #pragma unroll
    for (int off = 32; off > 0; off >>= 1) {
        lloc += __shfl_xor(lloc, off);
        lcnt += __shfl_xor(lcnt, off);
    }
    if (lane == 0 && lcnt > 0) {
        atomicAdd(&accum[1], (double)lloc);
        atomicAdd(&accum[2], (double)lcnt);
    }
}

// ---------------------------------------------------------------------------
// Kernel B1: streaming focal pass — ALL elements as negatives. No labels,
// no row tracking, no divergence. Pure 113 MB float4 stream (memory-bound).
// ---------------------------------------------------------------------------
__global__ __launch_bounds__(256) void focal_neg_kernel(
    const float* __restrict__ scores,
    double* __restrict__ accum)
{
    const unsigned total4 = (unsigned)(NB * NP * NCLS / 4);  // 7,076,160
    const float4* s4 = reinterpret_cast<const float4*>(scores);
    float lsum = 0.f;
    for (unsigned i = blockIdx.x * blockDim.x + threadIdx.x; i < total4;
         i += gridDim.x * blockDim.x) {
        float4 v = s4[i];
        lsum += focal_neg(v.x);
        lsum += focal_neg(v.y);
        lsum += focal_neg(v.z);
        lsum += focal_neg(v.w);
    }
    __shared__ float red[4];
    #pragma unroll
    for (int off = 32; off > 0; off >>= 1) lsum += __shfl_xor(lsum, off);
    int wid = threadIdx.x >> 6, lane = threadIdx.x & 63;
    if (lane == 0) red[wid] = lsum;
    __syncthreads();
    if (threadIdx.x == 0) {
        float t = red[0] + red[1] + red[2] + red[3];
        atomicAdd(&accum[0], (double)t);
    }
}

// ---------------------------------------------------------------------------
// Kernel B2: per-row correction at the one-hot slot: + pos(target) - neg(target).
// One thread per row (NB*NP = 349,440 = 1365 * 256 exactly).
// ---------------------------------------------------------------------------
__global__ __launch_bounds__(256) void fixup_kernel(
    const float* __restrict__ scores,
    const int* __restrict__ winner,   // [NB*NP] obj ids, -1 = background
    const int* __restrict__ labels,   // [NB, NO]
    double* __restrict__ accum)
{
    const int r = blockIdx.x * 256 + threadIdx.x;
    const int w = winner[r];
    const int L = (w >= 0) ? labels[(r / NP) * NO + w] : 0;
    const float s = scores[r * NCLS + L];
    double d = (double)focal_pos(s) - (double)focal_neg(s);

    __shared__ double redd[4];
    #pragma unroll
    for (int off = 32; off > 0; off >>= 1) d += __shfl_xor(d, off);
    int wid = threadIdx.x >> 6, lane = threadIdx.x & 63;
    if (lane == 0) redd[wid] = d;
    __syncthreads();
    if (threadIdx.x == 0) {
        atomicAdd(&accum[0], redd[0] + redd[1] + redd[2] + redd[3]);
    }
}

__global__ void finalize_kernel(const double* __restrict__ accum,
                                float* __restrict__ out)
{
    double conf = accum[0] / (double)(NB * NP);
    double cnt = accum[2];
    double loc = accum[1] / (cnt > 1.0 ? cnt : 1.0);
    out[0] = (float)(conf + loc);
}

extern "C" void kernel_launch(void* const* d_in, const int* in_sizes, int n_in,
                              void* d_out, int out_size, void* d_ws, size_t ws_size,
                              hipStream_t stream) {
    const float* locs   = (const float*)d_in[0];
    const float* scores = (const float*)d_in[1];
    const float* boxes  = (const float*)d_in[2];
    const int*   labels = (const int*)d_in[3];
    const float* priors = (const float*)d_in[4];
    float* out = (float*)d_out;

    double* accum = (double*)((char*)d_ws + WS_ACCUM);
    int*    winner = (int*)((char*)d_ws + WS_WINNER);
    int*    ci_buf = (int*)((char*)d_ws + WS_CI);
    float*  ov_buf = (float*)((char*)d_ws + WS_OV);

    hipMemsetAsync((char*)d_ws + WS_ACCUM, 0, 64, stream);
    hipMemsetAsync(winner, 0xFF, (size_t)NB * NP * sizeof(int), stream);

    topk_kernel<<<24, 256, 0, stream>>>(boxes, ci_buf, ov_buf);
    assign2_kernel<<<256, 256, 0, stream>>>(locs, boxes, priors, ci_buf, ov_buf,
                                            winner, accum);
    focal_neg_kernel<<<2048, 256, 0, stream>>>(scores, accum);
    fixup_kernel<<<NB * NP / 256, 256, 0, stream>>>(scores, winner, labels, accum);
    finalize_kernel<<<1, 1, 0, stream>>>(accum, out);
}